// Round 8
// baseline (395.084 us; speedup 1.0000x reference)
//
#include <hip/hip_runtime.h>
#include <cstdint>
#include <cstddef>

typedef unsigned int uint;
typedef unsigned short ushort;
typedef __attribute__((ext_vector_type(8))) short bf16x8;
typedef __attribute__((ext_vector_type(4))) float f32x4;

__device__ __forceinline__ ushort f2bf(float f) {          // RNE float->bf16
    uint b = __float_as_uint(f);
    return (ushort)((b + 0x7FFF + ((b >> 16) & 1)) >> 16);
}
__device__ __forceinline__ float bf_lo(uint u) { return __uint_as_float(u << 16); }
__device__ __forceinline__ float bf_hi(uint u) { return __uint_as_float(u & 0xFFFF0000u); }

// ============ CSR build via bucketed counting sort (no global atomics) ======
// bucket b = dst >> 8. NBKT <= 512, CHUNK <= 8192 assumed.

// P1: per-block coarse histogram -> cnt2d[b*256 + blk]; blocks >=256 do W-prep.
__global__ __launch_bounds__(256) void k_bcount(
        const int* __restrict__ dst, int E, int chunk,
        int* __restrict__ cnt2d, int nbkt,
        const float* __restrict__ W1, const float* __restrict__ W2,
        ushort* __restrict__ WT1, ushort* __restrict__ WT2,
        float* __restrict__ sums) {
    __shared__ int hist[512];
    if (blockIdx.x >= 256) {                    // fused weight prep + sums zero
        int idx = (blockIdx.x - 256) * 256 + threadIdx.x;   // 0..32767
        if (idx < 512) sums[idx] = 0.f;
        int nn = (idx >> 7) & 127, k = idx & 127;
        if (idx < 16384) WT1[idx] = f2bf(W1[k * 128 + nn]);
        else             WT2[idx - 16384] = f2bf(W2[k * 128 + nn]);
        return;
    }
    for (int b = threadIdx.x; b < nbkt; b += 256) hist[b] = 0;
    __syncthreads();
    const int beg = blockIdx.x * chunk;
    const int end = min(beg + chunk, E);
    for (int i = beg + threadIdx.x; i < end; i += 256)
        atomicAdd(&hist[dst[i] >> 8], 1);
    __syncthreads();
    for (int b = threadIdx.x; b < nbkt; b += 256)
        cnt2d[b * 256 + blockIdx.x] = hist[b];
}

// P2: LDS-staged scatter — locally bucket-sort the chunk, then write each
// (bucket,block) slice as a contiguous run.
__global__ __launch_bounds__(256) void k_bscatter(
        const int* __restrict__ src, const int* __restrict__ dst, int E, int chunk,
        const int* __restrict__ cnt2d, const int* __restrict__ cnt2dx,
        uint* __restrict__ ebuf, int nbkt) {
    __shared__ uint   ebuf_l[8192];
    __shared__ ushort bid_l[8192];
    __shared__ int    sh[256];
    __shared__ int    histx[512];
    __shared__ int    cur[512];
    __shared__ int    goff[512];
    const int t   = threadIdx.x;
    const int blk = blockIdx.x;

    const int b0 = 2 * t, b1 = 2 * t + 1;
    const int c0 = (b0 < nbkt) ? cnt2d[b0 * 256 + blk] : 0;
    const int c1 = (b1 < nbkt) ? cnt2d[b1 * 256 + blk] : 0;
    sh[t] = c0 + c1;
    __syncthreads();
    #pragma unroll
    for (int o = 1; o < 256; o <<= 1) {
        int x = (t >= o) ? sh[t - o] : 0;
        __syncthreads();
        sh[t] += x;
        __syncthreads();
    }
    const int ex = sh[t] - (c0 + c1);
    histx[b0] = ex;       histx[b1] = ex + c0;
    cur[b0]   = ex;       cur[b1]   = ex + c0;
    goff[b0] = ((b0 < nbkt) ? cnt2dx[b0 * 256 + blk] : 0) - histx[b0];
    goff[b1] = ((b1 < nbkt) ? cnt2dx[b1 * 256 + blk] : 0) - histx[b1];
    __syncthreads();

    const int beg = blk * chunk;
    const int end = min(beg + chunk, E);
    for (int i = beg + t; i < end; i += 256) {
        int d = dst[i];
        int s = src[i];
        int b = d >> 8;
        int p = atomicAdd(&cur[b], 1);            // LDS atomic
        ebuf_l[p] = ((uint)(d & 255) << 17) | (uint)s;
        bid_l[p]  = (ushort)b;
    }
    __syncthreads();

    const int cntE = end - beg;
    for (int i = t; i < cntE; i += 256)
        ebuf[goff[bid_l[i]] + i] = ebuf_l[i];
}

// P3: one block per bucket: fine counts -> dinv, offs, grouped csr
__global__ __launch_bounds__(256) void k_bcsr(
        const uint* __restrict__ ebuf, const int* __restrict__ cnt2dx,
        int E, int n, int nbkt,
        float* __restrict__ dinv, int* __restrict__ offs, int* __restrict__ csr) {
    __shared__ int fine[256], finex[256], fcur[256];
    const int b = blockIdx.x;
    const int t = threadIdx.x;
    const int ebeg = cnt2dx[b * 256];
    const int eend = (b + 1 < nbkt) ? cnt2dx[(b + 1) * 256] : E;
    fine[t] = 0;
    __syncthreads();
    for (int i = ebeg + t; i < eend; i += 256)
        atomicAdd(&fine[ebuf[i] >> 17], 1);
    __syncthreads();
    const int node = b * 256 + t;
    if (node < n) dinv[node] = rsqrtf((float)(fine[t] + 1));
    int v = fine[t];
    finex[t] = v;
    __syncthreads();
    #pragma unroll
    for (int o = 1; o < 256; o <<= 1) {
        int x = (t >= o) ? finex[t - o] : 0;
        __syncthreads();
        finex[t] += x;
        __syncthreads();
    }
    const int ex = finex[t] - v;
    fcur[t] = ex;
    if (node <= n) offs[node] = ebeg + ex;
    if (b == 0 && t == 0) offs[n] = E;
    __syncthreads();
    for (int i = ebeg + t; i < eend; i += 256) {
        uint e = ebuf[i];
        int f = (int)(e >> 17);
        int p = atomicAdd(&fcur[f], 1);             // LDS atomic
        csr[ebeg + p] = (int)(e & 0x1FFFF);
    }
}

// ---------------- hierarchical exclusive scan (used on cnt2d) --------------
__global__ __launch_bounds__(256) void k_scan_local(
        const int* __restrict__ cnt, int n,
        int* __restrict__ offs, int* __restrict__ bsum) {
    __shared__ int sh[256];
    const int base = blockIdx.x * 1024 + threadIdx.x * 4;
    int v[4];
    #pragma unroll
    for (int j = 0; j < 4; j++) { int g = base + j; v[j] = (g < n) ? cnt[g] : 0; }
    const int tsum = v[0] + v[1] + v[2] + v[3];
    sh[threadIdx.x] = tsum;
    __syncthreads();
    #pragma unroll
    for (int o = 1; o < 256; o <<= 1) {
        int t = (threadIdx.x >= (unsigned)o) ? sh[threadIdx.x - o] : 0;
        __syncthreads();
        sh[threadIdx.x] += t;
        __syncthreads();
    }
    int run = sh[threadIdx.x] - tsum;
    #pragma unroll
    for (int j = 0; j < 4; j++) {
        int g = base + j;
        if (g < n) offs[g] = run;
        run += v[j];
    }
    if (threadIdx.x == 255) bsum[blockIdx.x] = sh[255];
}

// add-back; each block derives its own prefix from bsum (nb <= 256)
__global__ __launch_bounds__(256) void k_scan_add(
        int* __restrict__ offs, int n, const int* __restrict__ bsum, int nb) {
    __shared__ int red[256];
    const int t = threadIdx.x;
    red[t] = (t < nb && t < (int)blockIdx.x) ? bsum[t] : 0;
    __syncthreads();
    #pragma unroll
    for (int o = 128; o; o >>= 1) {
        if (t < o) red[t] += red[t + o];
        __syncthreads();
    }
    const int add = red[0];
    const int base = blockIdx.x * 1024;
    #pragma unroll
    for (int j = 0; j < 4; j++) {
        int g = base + t + j * 256;
        if (g < n) offs[g] += add;
    }
}

// ---------------- MFMA GEMM: C[n,128](bf16) = dinv[r] * f(A) @ W -------------
template <int LAYER>
__global__ __launch_bounds__(256) void k_gemm(
        const void* __restrict__ Av, const ushort* __restrict__ WT,
        const float* __restrict__ sums, const float* __restrict__ g,
        const float* __restrict__ be, const float* __restrict__ dinv,
        ushort* __restrict__ C, int n, float invn) {
    __shared__ float ssl[256];
    const int tid = threadIdx.x;
    if (LAYER == 1) {
        if (tid < 128) {
            float mean = sums[tid] * invn;
            float var  = sums[128 + tid] * invn - mean * mean;
            float inv  = rsqrtf(var + 1e-5f);
            float sc   = g[tid] * inv;
            ssl[tid]       = sc;
            ssl[128 + tid] = be[tid] - mean * sc;
        }
        __syncthreads();
    }

    const int lane = tid & 63;
    const int wid  = tid >> 6;
    const int m0   = blockIdx.x * 64 + wid * 16;
    const int lm   = lane & 15;
    const int lq   = lane >> 4;
    const int row  = m0 + lm;
    const bool rv  = row < n;

    f32x4 acc[8];
    #pragma unroll
    for (int i = 0; i < 8; i++) acc[i] = (f32x4){0.f, 0.f, 0.f, 0.f};

    #pragma unroll
    for (int ks = 0; ks < 4; ks++) {
        const int kb = ks * 32 + lq * 8;
        bf16x8 af;
        if (LAYER == 0) {
            const float* A = (const float*)Av;
            float4 v0, v1;
            if (rv) {
                v0 = *(const float4*)&A[(size_t)row * 128 + kb];
                v1 = *(const float4*)&A[(size_t)row * 128 + kb + 4];
            } else {
                v0 = make_float4(0.f, 0.f, 0.f, 0.f);
                v1 = v0;
            }
            af[0] = (short)f2bf(v0.x); af[1] = (short)f2bf(v0.y);
            af[2] = (short)f2bf(v0.z); af[3] = (short)f2bf(v0.w);
            af[4] = (short)f2bf(v1.x); af[5] = (short)f2bf(v1.y);
            af[6] = (short)f2bf(v1.z); af[7] = (short)f2bf(v1.w);
        } else {
            const uint* A = (const uint*)Av;
            uint4 u = rv ? *(const uint4*)&A[(size_t)row * 64 + kb / 2]
                         : make_uint4(0, 0, 0, 0);
            float4 sc0 = *(const float4*)&ssl[kb];
            float4 sc1 = *(const float4*)&ssl[kb + 4];
            float4 sh0 = *(const float4*)&ssl[128 + kb];
            float4 sh1 = *(const float4*)&ssl[128 + kb + 4];
            float f0 = fmaxf(fmaf(bf_lo(u.x), sc0.x, sh0.x), 0.f);
            float f1 = fmaxf(fmaf(bf_hi(u.x), sc0.y, sh0.y), 0.f);
            float f2 = fmaxf(fmaf(bf_lo(u.y), sc0.z, sh0.z), 0.f);
            float f3 = fmaxf(fmaf(bf_hi(u.y), sc0.w, sh0.w), 0.f);
            float f4 = fmaxf(fmaf(bf_lo(u.z), sc1.x, sh1.x), 0.f);
            float f5 = fmaxf(fmaf(bf_hi(u.z), sc1.y, sh1.y), 0.f);
            float f6 = fmaxf(fmaf(bf_lo(u.w), sc1.z, sh1.z), 0.f);
            float f7 = fmaxf(fmaf(bf_hi(u.w), sc1.w, sh1.w), 0.f);
            af[0] = (short)f2bf(f0); af[1] = (short)f2bf(f1);
            af[2] = (short)f2bf(f2); af[3] = (short)f2bf(f3);
            af[4] = (short)f2bf(f4); af[5] = (short)f2bf(f5);
            af[6] = (short)f2bf(f6); af[7] = (short)f2bf(f7);
        }
        #pragma unroll
        for (int nt = 0; nt < 8; nt++) {
            bf16x8 bfr = *(const bf16x8*)&WT[(size_t)(nt * 16 + lm) * 128 + kb];
            acc[nt] = __builtin_amdgcn_mfma_f32_16x16x32_bf16(af, bfr, acc[nt], 0, 0, 0);
        }
    }

    const int orow0 = m0 + lq * 4;
    #pragma unroll
    for (int r = 0; r < 4; r++) {
        const int orow = orow0 + r;
        if (orow < n) {
            const float s = dinv[orow];
            #pragma unroll
            for (int nt = 0; nt < 8; nt++)
                C[(size_t)orow * 128 + nt * 16 + lm] = f2bf(acc[nt][r] * s);
        }
    }
}

// ---------------- gather-aggregate: XCD feature-split -----------------------
// blockIdx%8 in {0..3} -> feature half 0 (XCDs 0-3); {4..7} -> half 1.
// Per wave: one node's 128B half-row. lane=(q in 0..7: 16B chunk, eg in 0..7:
// edge slot) -> 8 edges per wave-load instruction; shfl-reduce over eg.
__global__ __launch_bounds__(256) void k_gather(
        const uint* __restrict__ hs, const int* __restrict__ offs,
        const int* __restrict__ csr, const float* __restrict__ dinv,
        const float* __restrict__ bias, uint* __restrict__ out, int n) {
    const int b    = blockIdx.x;
    const int half = (b >> 2) & 1;                  // b%8: 0-3 -> 0, 4-7 -> 1
    const int nb   = (b >> 3) * 4 + (b & 3);        // node-block within half
    const int node = nb * 4 + (threadIdx.x >> 6);
    if (node >= n) return;
    const int lane = threadIdx.x & 63;
    const int q  = lane & 7;
    const int eg = lane >> 3;
    const int beg = offs[node], end = offs[node + 1];
    const uint4* hs4 = (const uint4*)hs;
    const int rowOff = half * 8;                    // uint4 offset within row

    float acc[8];
    if (eg == 0) {                                  // self loop (prescaled)
        uint4 sv = hs4[(size_t)node * 16 + rowOff + q];
        acc[0] = bf_lo(sv.x); acc[1] = bf_hi(sv.x);
        acc[2] = bf_lo(sv.y); acc[3] = bf_hi(sv.y);
        acc[4] = bf_lo(sv.z); acc[5] = bf_hi(sv.z);
        acc[6] = bf_lo(sv.w); acc[7] = bf_hi(sv.w);
    } else {
        #pragma unroll
        for (int j = 0; j < 8; j++) acc[j] = 0.f;
    }

    for (int e = beg + eg; e < end; e += 8) {
        const int s = csr[e];
        uint4 v = hs4[(size_t)s * 16 + rowOff + q];
        acc[0] += bf_lo(v.x); acc[1] += bf_hi(v.x);
        acc[2] += bf_lo(v.y); acc[3] += bf_hi(v.y);
        acc[4] += bf_lo(v.z); acc[5] += bf_hi(v.z);
        acc[6] += bf_lo(v.w); acc[7] += bf_hi(v.w);
    }

    #pragma unroll
    for (int j = 0; j < 8; j++) {
        acc[j] += __shfl_xor(acc[j], 8);
        acc[j] += __shfl_xor(acc[j], 16);
        acc[j] += __shfl_xor(acc[j], 32);
    }

    if (eg == 0) {
        const float di = dinv[node];
        const int c0 = half * 64 + q * 8;
        const float4 b0 = *(const float4*)&bias[c0];
        const float4 b1 = *(const float4*)&bias[c0 + 4];
        uint4 o;
        o.x = (uint)f2bf(fmaf(di, acc[0], b0.x)) | ((uint)f2bf(fmaf(di, acc[1], b0.y)) << 16);
        o.y = (uint)f2bf(fmaf(di, acc[2], b0.z)) | ((uint)f2bf(fmaf(di, acc[3], b0.w)) << 16);
        o.z = (uint)f2bf(fmaf(di, acc[4], b1.x)) | ((uint)f2bf(fmaf(di, acc[5], b1.y)) << 16);
        o.w = (uint)f2bf(fmaf(di, acc[6], b1.z)) | ((uint)f2bf(fmaf(di, acc[7], b1.w)) << 16);
        ((uint4*)out)[(size_t)node * 16 + rowOff + q] = o;
    }
}

// ---------------- BN stats (packed uint loads) ----------------
__global__ __launch_bounds__(256) void k_stats(
        const uint* __restrict__ h, int n, float* __restrict__ sums) {
    const int j   = threadIdx.x & 63;
    const int sub = threadIdx.x >> 6;
    float slo = 0.f, s2lo = 0.f, shi = 0.f, s2hi = 0.f;
    for (int r = blockIdx.x * 4 + sub; r < n; r += gridDim.x * 4) {
        uint u = h[(size_t)r * 64 + j];
        float a = bf_lo(u), b = bf_hi(u);
        slo += a; s2lo = fmaf(a, a, s2lo);
        shi += b; s2hi = fmaf(b, b, s2hi);
    }
    __shared__ float sh[4][256];
    sh[0][threadIdx.x] = slo; sh[1][threadIdx.x] = s2lo;
    sh[2][threadIdx.x] = shi; sh[3][threadIdx.x] = s2hi;
    __syncthreads();
    if (sub == 0) {
        float a0 = 0.f, a1 = 0.f, a2 = 0.f, a3 = 0.f;
        #pragma unroll
        for (int t = 0; t < 4; t++) {
            a0 += sh[0][t * 64 + j]; a1 += sh[1][t * 64 + j];
            a2 += sh[2][t * 64 + j]; a3 += sh[3][t * 64 + j];
        }
        atomicAdd(&sums[2 * j],           a0);
        atomicAdd(&sums[128 + 2 * j],     a1);
        atomicAdd(&sums[2 * j + 1],       a2);
        atomicAdd(&sums[128 + 2 * j + 1], a3);
    }
}

// ---------------- head (BN2 derived in-block) --------------
__global__ __launch_bounds__(1024) void k_final(
        const uint* __restrict__ h, const float* __restrict__ sums,
        const float* __restrict__ g, const float* __restrict__ be,
        const float* __restrict__ Wl, const float* __restrict__ bl,
        float* __restrict__ out, int n, float invn) {
    __shared__ float ssl[256];
    const int t = threadIdx.x;
    if (t < 128) {
        float mean = sums[t] * invn;
        float var  = sums[128 + t] * invn - mean * mean;
        float inv  = rsqrtf(var + 1e-5f);
        float sc   = g[t] * inv;
        ssl[t]       = sc;
        ssl[128 + t] = be[t] - mean * sc;
    }
    __syncthreads();
    int node = (blockIdx.x * 1024 + t) >> 6;
    int lane = t & 63;
    if (node >= n) return;
    int c = lane * 2;
    uint v = h[(size_t)node * 64 + lane];
    float a0 = fmaxf(fmaf(bf_lo(v), ssl[c],     ssl[128 + c]),     0.f);
    float a1 = fmaxf(fmaf(bf_hi(v), ssl[c + 1], ssl[128 + c + 1]), 0.f);
    float p = a0 * Wl[c] + a1 * Wl[c + 1];
    #pragma unroll
    for (int o = 32; o; o >>= 1) p += __shfl_xor(p, o);
    if (lane == 0) {
        float z = fmaxf(p + bl[0], 0.f);
        out[node] = 1.f / (1.f + expf(-z));
    }
}

extern "C" void kernel_launch(void* const* d_in, const int* in_sizes, int n_in,
                              void* d_out, int out_size, void* d_ws, size_t ws_size,
                              hipStream_t stream) {
    const float* x   = (const float*)d_in[0];
    const int*   ei  = (const int*)d_in[1];
    const float* W1  = (const float*)d_in[2];
    const float* b1  = (const float*)d_in[3];
    const float* g1  = (const float*)d_in[4];
    const float* be1 = (const float*)d_in[5];
    const float* W2  = (const float*)d_in[6];
    const float* b2  = (const float*)d_in[7];
    const float* g2  = (const float*)d_in[8];
    const float* be2 = (const float*)d_in[9];
    const float* Wl  = (const float*)d_in[10];
    const float* bl  = (const float*)d_in[11];

    const int N = in_sizes[0] / 128;
    const int E = in_sizes[1] / 2;
    const int* src  = ei;
    const int* dstp = ei + E;

    const int NBKT  = (N + 255) >> 8;
    const int n2    = NBKT * 256;
    const int NB2   = (n2 + 1023) / 1024;
    const int CHUNK = (E + 255) / 256;

    // feature-split gather grid: 2 halves x NBH node-blocks (4 nodes each)
    const int NBH  = (N + 3) / 4;
    const int NBH4 = (NBH + 3) & ~3;
    const int GGRID = 2 * NBH4;

    char* ws = (char*)d_ws;
    size_t off = 0;
    auto alloc = [&](size_t bytes) {
        void* p = ws + off;
        off += (bytes + 255) & ~(size_t)255;
        return p;
    };
    float*  dinv   = (float*) alloc((size_t)N * 4);
    int*    offs   = (int*)   alloc((size_t)(N + 1) * 4);
    int*    cnt2d  = (int*)   alloc((size_t)n2 * 4);
    int*    cnt2dx = (int*)   alloc((size_t)n2 * 4);
    int*    bsum   = (int*)   alloc(1024 * 4);
    uint*   ebuf   = (uint*)  alloc((size_t)E * 4);
    int*    csr    = (int*)   alloc((size_t)E * 4);
    float*  sums   = (float*) alloc(512 * 4);
    ushort* WT1    = (ushort*)alloc(128 * 128 * 2);
    ushort* WT2    = (ushort*)alloc(128 * 128 * 2);
    ushort* hbuf   = (ushort*)alloc((size_t)N * 128 * 2);
    ushort* abuf   = (ushort*)alloc((size_t)N * 128 * 2);

    const float invn = 1.f / (float)N;

    // ---- CSR build (bucketed counting sort) + fused weight prep ----
    k_bcount    <<<384, 256, 0, stream>>>(dstp, E, CHUNK, cnt2d, NBKT,
                                          W1, W2, WT1, WT2, sums);
    k_scan_local<<<NB2, 256, 0, stream>>>(cnt2d, n2, cnt2dx, bsum);
    k_scan_add  <<<NB2, 256, 0, stream>>>(cnt2dx, n2, bsum, NB2);
    k_bscatter  <<<256, 256, 0, stream>>>(src, dstp, E, CHUNK, cnt2d, cnt2dx, ebuf, NBKT);
    k_bcsr      <<<NBKT, 256, 0, stream>>>(ebuf, cnt2dx, E, N, NBKT, dinv, offs, csr);

    // ---- layer 1 ----
    k_gemm<0> <<<(N + 63) / 64, 256, 0, stream>>>(x, WT1, nullptr, nullptr, nullptr, dinv, hbuf, N, invn);
    k_gather  <<<GGRID, 256, 0, stream>>>((const uint*)hbuf, offs, csr, dinv, b1, (uint*)abuf, N);
    k_stats   <<<512, 256, 0, stream>>>((const uint*)abuf, N, sums);

    // ---- layer 2 (BN1+ReLU and BN-param derivation fused into GEMM2) ----
    k_gemm<1> <<<(N + 63) / 64, 256, 0, stream>>>(abuf, WT2, sums, g1, be1, dinv, hbuf, N, invn);
    k_gather  <<<GGRID, 256, 0, stream>>>((const uint*)hbuf, offs, csr, dinv, b2, (uint*)abuf, N);
    k_stats   <<<512, 256, 0, stream>>>((const uint*)abuf, N, sums + 256);

    // ---- head (BN2 derived in-block) ----
    k_final<<<(N + 15) / 16, 1024, 0, stream>>>((const uint*)abuf, sums + 256, g2, be2, Wl, bl, (float*)d_out, N, invn);
}

// Round 9
// 377.755 us; speedup vs baseline: 1.0459x; 1.0459x over previous
//
#include <hip/hip_runtime.h>
#include <cstdint>
#include <cstddef>

typedef unsigned int uint;
typedef unsigned short ushort;
typedef __attribute__((ext_vector_type(8))) short bf16x8;
typedef __attribute__((ext_vector_type(4))) float f32x4;

__device__ __forceinline__ ushort f2bf(float f) {          // RNE float->bf16
    uint b = __float_as_uint(f);
    return (ushort)((b + 0x7FFF + ((b >> 16) & 1)) >> 16);
}
__device__ __forceinline__ float bf_lo(uint u) { return __uint_as_float(u << 16); }
__device__ __forceinline__ float bf_hi(uint u) { return __uint_as_float(u & 0xFFFF0000u); }

// ============ CSR build via bucketed counting sort (no global atomics) ======
// bucket b = dst >> 8. NBKT <= 512, CHUNK <= 8192 assumed.

// P1: per-block coarse histogram -> cnt2d[b*256 + blk]; blocks >=256 do W-prep.
__global__ __launch_bounds__(256) void k_bcount(
        const int* __restrict__ dst, int E, int chunk,
        int* __restrict__ cnt2d, int nbkt,
        const float* __restrict__ W1, const float* __restrict__ W2,
        ushort* __restrict__ WT1, ushort* __restrict__ WT2,
        float* __restrict__ sums) {
    __shared__ int hist[512];
    if (blockIdx.x >= 256) {                    // fused weight prep + sums zero
        int idx = (blockIdx.x - 256) * 256 + threadIdx.x;   // 0..32767
        if (idx < 512) sums[idx] = 0.f;
        int nn = (idx >> 7) & 127, k = idx & 127;
        if (idx < 16384) WT1[idx] = f2bf(W1[k * 128 + nn]);
        else             WT2[idx - 16384] = f2bf(W2[k * 128 + nn]);
        return;
    }
    for (int b = threadIdx.x; b < nbkt; b += 256) hist[b] = 0;
    __syncthreads();
    const int beg = blockIdx.x * chunk;
    const int end = min(beg + chunk, E);
    for (int i = beg + threadIdx.x; i < end; i += 256)
        atomicAdd(&hist[dst[i] >> 8], 1);
    __syncthreads();
    for (int b = threadIdx.x; b < nbkt; b += 256)
        cnt2d[b * 256 + blockIdx.x] = hist[b];
}

// P2: LDS-staged scatter — locally bucket-sort the chunk, then write each
// (bucket,block) slice as a contiguous run.
__global__ __launch_bounds__(256) void k_bscatter(
        const int* __restrict__ src, const int* __restrict__ dst, int E, int chunk,
        const int* __restrict__ cnt2d, const int* __restrict__ cnt2dx,
        uint* __restrict__ ebuf, int nbkt) {
    __shared__ uint   ebuf_l[8192];
    __shared__ ushort bid_l[8192];
    __shared__ int    sh[256];
    __shared__ int    histx[512];
    __shared__ int    cur[512];
    __shared__ int    goff[512];
    const int t   = threadIdx.x;
    const int blk = blockIdx.x;

    const int b0 = 2 * t, b1 = 2 * t + 1;
    const int c0 = (b0 < nbkt) ? cnt2d[b0 * 256 + blk] : 0;
    const int c1 = (b1 < nbkt) ? cnt2d[b1 * 256 + blk] : 0;
    sh[t] = c0 + c1;
    __syncthreads();
    #pragma unroll
    for (int o = 1; o < 256; o <<= 1) {
        int x = (t >= o) ? sh[t - o] : 0;
        __syncthreads();
        sh[t] += x;
        __syncthreads();
    }
    const int ex = sh[t] - (c0 + c1);
    histx[b0] = ex;       histx[b1] = ex + c0;
    cur[b0]   = ex;       cur[b1]   = ex + c0;
    goff[b0] = ((b0 < nbkt) ? cnt2dx[b0 * 256 + blk] : 0) - histx[b0];
    goff[b1] = ((b1 < nbkt) ? cnt2dx[b1 * 256 + blk] : 0) - histx[b1];
    __syncthreads();

    const int beg = blk * chunk;
    const int end = min(beg + chunk, E);
    for (int i = beg + t; i < end; i += 256) {
        int d = dst[i];
        int s = src[i];
        int b = d >> 8;
        int p = atomicAdd(&cur[b], 1);            // LDS atomic
        ebuf_l[p] = ((uint)(d & 255) << 17) | (uint)s;
        bid_l[p]  = (ushort)b;
    }
    __syncthreads();

    const int cntE = end - beg;
    for (int i = t; i < cntE; i += 256)
        ebuf[goff[bid_l[i]] + i] = ebuf_l[i];
}

// P3: one block per bucket: fine counts -> dinv, offs, grouped csr
__global__ __launch_bounds__(256) void k_bcsr(
        const uint* __restrict__ ebuf, const int* __restrict__ cnt2dx,
        int E, int n, int nbkt,
        float* __restrict__ dinv, int* __restrict__ offs, int* __restrict__ csr) {
    __shared__ int fine[256], finex[256], fcur[256];
    const int b = blockIdx.x;
    const int t = threadIdx.x;
    const int ebeg = cnt2dx[b * 256];
    const int eend = (b + 1 < nbkt) ? cnt2dx[(b + 1) * 256] : E;
    fine[t] = 0;
    __syncthreads();
    for (int i = ebeg + t; i < eend; i += 256)
        atomicAdd(&fine[ebuf[i] >> 17], 1);
    __syncthreads();
    const int node = b * 256 + t;
    if (node < n) dinv[node] = rsqrtf((float)(fine[t] + 1));
    int v = fine[t];
    finex[t] = v;
    __syncthreads();
    #pragma unroll
    for (int o = 1; o < 256; o <<= 1) {
        int x = (t >= o) ? finex[t - o] : 0;
        __syncthreads();
        finex[t] += x;
        __syncthreads();
    }
    const int ex = finex[t] - v;
    fcur[t] = ex;
    if (node <= n) offs[node] = ebeg + ex;
    if (b == 0 && t == 0) offs[n] = E;
    __syncthreads();
    for (int i = ebeg + t; i < eend; i += 256) {
        uint e = ebuf[i];
        int f = (int)(e >> 17);
        int p = atomicAdd(&fcur[f], 1);             // LDS atomic
        csr[ebeg + p] = (int)(e & 0x1FFFF);
    }
}

// ---------------- hierarchical exclusive scan (used on cnt2d) --------------
__global__ __launch_bounds__(256) void k_scan_local(
        const int* __restrict__ cnt, int n,
        int* __restrict__ offs, int* __restrict__ bsum) {
    __shared__ int sh[256];
    const int base = blockIdx.x * 1024 + threadIdx.x * 4;
    int v[4];
    #pragma unroll
    for (int j = 0; j < 4; j++) { int g = base + j; v[j] = (g < n) ? cnt[g] : 0; }
    const int tsum = v[0] + v[1] + v[2] + v[3];
    sh[threadIdx.x] = tsum;
    __syncthreads();
    #pragma unroll
    for (int o = 1; o < 256; o <<= 1) {
        int t = (threadIdx.x >= (unsigned)o) ? sh[threadIdx.x - o] : 0;
        __syncthreads();
        sh[threadIdx.x] += t;
        __syncthreads();
    }
    int run = sh[threadIdx.x] - tsum;
    #pragma unroll
    for (int j = 0; j < 4; j++) {
        int g = base + j;
        if (g < n) offs[g] = run;
        run += v[j];
    }
    if (threadIdx.x == 255) bsum[blockIdx.x] = sh[255];
}

// add-back; each block derives its own prefix from bsum (nb <= 256)
__global__ __launch_bounds__(256) void k_scan_add(
        int* __restrict__ offs, int n, const int* __restrict__ bsum, int nb) {
    __shared__ int red[256];
    const int t = threadIdx.x;
    red[t] = (t < nb && t < (int)blockIdx.x) ? bsum[t] : 0;
    __syncthreads();
    #pragma unroll
    for (int o = 128; o; o >>= 1) {
        if (t < o) red[t] += red[t + o];
        __syncthreads();
    }
    const int add = red[0];
    const int base = blockIdx.x * 1024;
    #pragma unroll
    for (int j = 0; j < 4; j++) {
        int g = base + t + j * 256;
        if (g < n) offs[g] += add;
    }
}

// ---------------- MFMA GEMM: C[n,128](bf16) = dinv[r] * f(A) @ W -------------
template <int LAYER>
__global__ __launch_bounds__(256) void k_gemm(
        const void* __restrict__ Av, const ushort* __restrict__ WT,
        const float* __restrict__ sums, const float* __restrict__ g,
        const float* __restrict__ be, const float* __restrict__ dinv,
        ushort* __restrict__ C, int n, float invn) {
    __shared__ float ssl[256];
    const int tid = threadIdx.x;
    if (LAYER == 1) {
        if (tid < 128) {
            float mean = sums[tid] * invn;
            float var  = sums[128 + tid] * invn - mean * mean;
            float inv  = rsqrtf(var + 1e-5f);
            float sc   = g[tid] * inv;
            ssl[tid]       = sc;
            ssl[128 + tid] = be[tid] - mean * sc;
        }
        __syncthreads();
    }

    const int lane = tid & 63;
    const int wid  = tid >> 6;
    const int m0   = blockIdx.x * 64 + wid * 16;
    const int lm   = lane & 15;
    const int lq   = lane >> 4;
    const int row  = m0 + lm;
    const bool rv  = row < n;

    f32x4 acc[8];
    #pragma unroll
    for (int i = 0; i < 8; i++) acc[i] = (f32x4){0.f, 0.f, 0.f, 0.f};

    #pragma unroll
    for (int ks = 0; ks < 4; ks++) {
        const int kb = ks * 32 + lq * 8;
        bf16x8 af;
        if (LAYER == 0) {
            const float* A = (const float*)Av;
            float4 v0, v1;
            if (rv) {
                v0 = *(const float4*)&A[(size_t)row * 128 + kb];
                v1 = *(const float4*)&A[(size_t)row * 128 + kb + 4];
            } else {
                v0 = make_float4(0.f, 0.f, 0.f, 0.f);
                v1 = v0;
            }
            af[0] = (short)f2bf(v0.x); af[1] = (short)f2bf(v0.y);
            af[2] = (short)f2bf(v0.z); af[3] = (short)f2bf(v0.w);
            af[4] = (short)f2bf(v1.x); af[5] = (short)f2bf(v1.y);
            af[6] = (short)f2bf(v1.z); af[7] = (short)f2bf(v1.w);
        } else {
            const uint* A = (const uint*)Av;
            uint4 u = rv ? *(const uint4*)&A[(size_t)row * 64 + kb / 2]
                         : make_uint4(0, 0, 0, 0);
            float4 sc0 = *(const float4*)&ssl[kb];
            float4 sc1 = *(const float4*)&ssl[kb + 4];
            float4 sh0 = *(const float4*)&ssl[128 + kb];
            float4 sh1 = *(const float4*)&ssl[128 + kb + 4];
            float f0 = fmaxf(fmaf(bf_lo(u.x), sc0.x, sh0.x), 0.f);
            float f1 = fmaxf(fmaf(bf_hi(u.x), sc0.y, sh0.y), 0.f);
            float f2 = fmaxf(fmaf(bf_lo(u.y), sc0.z, sh0.z), 0.f);
            float f3 = fmaxf(fmaf(bf_hi(u.y), sc0.w, sh0.w), 0.f);
            float f4 = fmaxf(fmaf(bf_lo(u.z), sc1.x, sh1.x), 0.f);
            float f5 = fmaxf(fmaf(bf_hi(u.z), sc1.y, sh1.y), 0.f);
            float f6 = fmaxf(fmaf(bf_lo(u.w), sc1.z, sh1.z), 0.f);
            float f7 = fmaxf(fmaf(bf_hi(u.w), sc1.w, sh1.w), 0.f);
            af[0] = (short)f2bf(f0); af[1] = (short)f2bf(f1);
            af[2] = (short)f2bf(f2); af[3] = (short)f2bf(f3);
            af[4] = (short)f2bf(f4); af[5] = (short)f2bf(f5);
            af[6] = (short)f2bf(f6); af[7] = (short)f2bf(f7);
        }
        #pragma unroll
        for (int nt = 0; nt < 8; nt++) {
            bf16x8 bfr = *(const bf16x8*)&WT[(size_t)(nt * 16 + lm) * 128 + kb];
            acc[nt] = __builtin_amdgcn_mfma_f32_16x16x32_bf16(af, bfr, acc[nt], 0, 0, 0);
        }
    }

    const int orow0 = m0 + lq * 4;
    #pragma unroll
    for (int r = 0; r < 4; r++) {
        const int orow = orow0 + r;
        if (orow < n) {
            const float s = dinv[orow];
            #pragma unroll
            for (int nt = 0; nt < 8; nt++)
                C[(size_t)orow * 128 + nt * 16 + lm] = f2bf(acc[nt][r] * s);
        }
    }
}

// ---------------- gather-aggregate: wave per node, uint4 lanes --------------
// Processes nodes [node0, node0+cnt). lane=(q in 0..15: 16B chunk, eg in
// 0..3: edge slot); 4 edges per wave-load; shfl-reduce across eg.
__global__ __launch_bounds__(256) void k_gather(
        const uint* __restrict__ hs, const int* __restrict__ offs,
        const int* __restrict__ csr, const float* __restrict__ dinv,
        const float* __restrict__ bias, uint* __restrict__ out,
        int node0, int cnt) {
    const int rel = (blockIdx.x * 256 + threadIdx.x) >> 6;
    if (rel >= cnt) return;
    const int node = node0 + rel;
    const int lane = threadIdx.x & 63;
    const int q  = lane & 15;
    const int eg = lane >> 4;
    const int beg = offs[node], end = offs[node + 1];
    const uint4* hs4 = (const uint4*)hs;

    float acc[8];
    if (eg == 0) {                               // self loop (prescaled rows)
        uint4 sv = hs4[(size_t)node * 16 + q];
        acc[0] = bf_lo(sv.x); acc[1] = bf_hi(sv.x);
        acc[2] = bf_lo(sv.y); acc[3] = bf_hi(sv.y);
        acc[4] = bf_lo(sv.z); acc[5] = bf_hi(sv.z);
        acc[6] = bf_lo(sv.w); acc[7] = bf_hi(sv.w);
    } else {
        #pragma unroll
        for (int j = 0; j < 8; j++) acc[j] = 0.f;
    }

    for (int e = beg + eg; e < end; e += 4) {
        const int s = csr[e];
        uint4 v = hs4[(size_t)s * 16 + q];
        acc[0] += bf_lo(v.x); acc[1] += bf_hi(v.x);
        acc[2] += bf_lo(v.y); acc[3] += bf_hi(v.y);
        acc[4] += bf_lo(v.z); acc[5] += bf_hi(v.z);
        acc[6] += bf_lo(v.w); acc[7] += bf_hi(v.w);
    }

    #pragma unroll
    for (int j = 0; j < 8; j++) {
        acc[j] += __shfl_xor(acc[j], 16);
        acc[j] += __shfl_xor(acc[j], 32);
    }

    if (eg == 0) {
        const float di = dinv[node];
        const float4 b0 = *(const float4*)&bias[q * 8];
        const float4 b1 = *(const float4*)&bias[q * 8 + 4];
        uint4 o;
        o.x = (uint)f2bf(fmaf(di, acc[0], b0.x)) | ((uint)f2bf(fmaf(di, acc[1], b0.y)) << 16);
        o.y = (uint)f2bf(fmaf(di, acc[2], b0.z)) | ((uint)f2bf(fmaf(di, acc[3], b0.w)) << 16);
        o.z = (uint)f2bf(fmaf(di, acc[4], b1.x)) | ((uint)f2bf(fmaf(di, acc[5], b1.y)) << 16);
        o.w = (uint)f2bf(fmaf(di, acc[6], b1.z)) | ((uint)f2bf(fmaf(di, acc[7], b1.w)) << 16);
        ((uint4*)out)[(size_t)node * 16 + q] = o;
    }
}

// ---------------- BN stats (packed uint loads) ----------------
__global__ __launch_bounds__(256) void k_stats(
        const uint* __restrict__ h, int n, float* __restrict__ sums) {
    const int j   = threadIdx.x & 63;
    const int sub = threadIdx.x >> 6;
    float slo = 0.f, s2lo = 0.f, shi = 0.f, s2hi = 0.f;
    for (int r = blockIdx.x * 4 + sub; r < n; r += gridDim.x * 4) {
        uint u = h[(size_t)r * 64 + j];
        float a = bf_lo(u), b = bf_hi(u);
        slo += a; s2lo = fmaf(a, a, s2lo);
        shi += b; s2hi = fmaf(b, b, s2hi);
    }
    __shared__ float sh[4][256];
    sh[0][threadIdx.x] = slo; sh[1][threadIdx.x] = s2lo;
    sh[2][threadIdx.x] = shi; sh[3][threadIdx.x] = s2hi;
    __syncthreads();
    if (sub == 0) {
        float a0 = 0.f, a1 = 0.f, a2 = 0.f, a3 = 0.f;
        #pragma unroll
        for (int t = 0; t < 4; t++) {
            a0 += sh[0][t * 64 + j]; a1 += sh[1][t * 64 + j];
            a2 += sh[2][t * 64 + j]; a3 += sh[3][t * 64 + j];
        }
        atomicAdd(&sums[2 * j],           a0);
        atomicAdd(&sums[128 + 2 * j],     a1);
        atomicAdd(&sums[2 * j + 1],       a2);
        atomicAdd(&sums[128 + 2 * j + 1], a3);
    }
}

// ---------------- head (BN2 derived in-block) --------------
__global__ __launch_bounds__(1024) void k_final(
        const uint* __restrict__ h, const float* __restrict__ sums,
        const float* __restrict__ g, const float* __restrict__ be,
        const float* __restrict__ Wl, const float* __restrict__ bl,
        float* __restrict__ out, int n, float invn) {
    __shared__ float ssl[256];
    const int t = threadIdx.x;
    if (t < 128) {
        float mean = sums[t] * invn;
        float var  = sums[128 + t] * invn - mean * mean;
        float inv  = rsqrtf(var + 1e-5f);
        float sc   = g[t] * inv;
        ssl[t]       = sc;
        ssl[128 + t] = be[t] - mean * sc;
    }
    __syncthreads();
    int node = (blockIdx.x * 1024 + t) >> 6;
    int lane = t & 63;
    if (node >= n) return;
    int c = lane * 2;
    uint v = h[(size_t)node * 64 + lane];
    float a0 = fmaxf(fmaf(bf_lo(v), ssl[c],     ssl[128 + c]),     0.f);
    float a1 = fmaxf(fmaf(bf_hi(v), ssl[c + 1], ssl[128 + c + 1]), 0.f);
    float p = a0 * Wl[c] + a1 * Wl[c + 1];
    #pragma unroll
    for (int o = 32; o; o >>= 1) p += __shfl_xor(p, o);
    if (lane == 0) {
        float z = fmaxf(p + bl[0], 0.f);
        out[node] = 1.f / (1.f + expf(-z));
    }
}

extern "C" void kernel_launch(void* const* d_in, const int* in_sizes, int n_in,
                              void* d_out, int out_size, void* d_ws, size_t ws_size,
                              hipStream_t stream) {
    const float* x   = (const float*)d_in[0];
    const int*   ei  = (const int*)d_in[1];
    const float* W1  = (const float*)d_in[2];
    const float* b1  = (const float*)d_in[3];
    const float* g1  = (const float*)d_in[4];
    const float* be1 = (const float*)d_in[5];
    const float* W2  = (const float*)d_in[6];
    const float* b2  = (const float*)d_in[7];
    const float* g2  = (const float*)d_in[8];
    const float* be2 = (const float*)d_in[9];
    const float* Wl  = (const float*)d_in[10];
    const float* bl  = (const float*)d_in[11];

    const int N = in_sizes[0] / 128;
    const int E = in_sizes[1] / 2;
    const int* src  = ei;
    const int* dstp = ei + E;

    const int NBKT  = (N + 255) >> 8;
    const int n2    = NBKT * 256;
    const int NB2   = (n2 + 1023) / 1024;
    const int CHUNK = (E + 255) / 256;

    // gather split into thirds (diagnostic: surfaces middle-tier kernels)
    const int T1 = N / 3, T2 = 2 * N / 3;
    const int C0 = T1, C1 = T2 - T1, C2 = N - T2;

    char* ws = (char*)d_ws;
    size_t off = 0;
    auto alloc = [&](size_t bytes) {
        void* p = ws + off;
        off += (bytes + 255) & ~(size_t)255;
        return p;
    };
    float*  dinv   = (float*) alloc((size_t)N * 4);
    int*    offs   = (int*)   alloc((size_t)(N + 1) * 4);
    int*    cnt2d  = (int*)   alloc((size_t)n2 * 4);
    int*    cnt2dx = (int*)   alloc((size_t)n2 * 4);
    int*    bsum   = (int*)   alloc(1024 * 4);
    uint*   ebuf   = (uint*)  alloc((size_t)E * 4);
    int*    csr    = (int*)   alloc((size_t)E * 4);
    float*  sums   = (float*) alloc(512 * 4);
    ushort* WT1    = (ushort*)alloc(128 * 128 * 2);
    ushort* WT2    = (ushort*)alloc(128 * 128 * 2);
    ushort* hbuf   = (ushort*)alloc((size_t)N * 128 * 2);
    ushort* abuf   = (ushort*)alloc((size_t)N * 128 * 2);

    const float invn = 1.f / (float)N;

    // ---- CSR build (bucketed counting sort) + fused weight prep ----
    k_bcount    <<<384, 256, 0, stream>>>(dstp, E, CHUNK, cnt2d, NBKT,
                                          W1, W2, WT1, WT2, sums);
    k_scan_local<<<NB2, 256, 0, stream>>>(cnt2d, n2, cnt2dx, bsum);
    k_scan_add  <<<NB2, 256, 0, stream>>>(cnt2dx, n2, bsum, NB2);
    k_bscatter  <<<256, 256, 0, stream>>>(src, dstp, E, CHUNK, cnt2d, cnt2dx, ebuf, NBKT);
    k_bcsr      <<<NBKT, 256, 0, stream>>>(ebuf, cnt2dx, E, N, NBKT, dinv, offs, csr);

    // ---- layer 1 ----
    k_gemm<0> <<<(N + 63) / 64, 256, 0, stream>>>(x, WT1, nullptr, nullptr, nullptr, dinv, hbuf, N, invn);
    k_gather  <<<(C0 + 3) / 4, 256, 0, stream>>>((const uint*)hbuf, offs, csr, dinv, b1, (uint*)abuf, 0,  C0);
    k_gather  <<<(C1 + 3) / 4, 256, 0, stream>>>((const uint*)hbuf, offs, csr, dinv, b1, (uint*)abuf, T1, C1);
    k_gather  <<<(C2 + 3) / 4, 256, 0, stream>>>((const uint*)hbuf, offs, csr, dinv, b1, (uint*)abuf, T2, C2);
    k_stats   <<<512, 256, 0, stream>>>((const uint*)abuf, N, sums);

    // ---- layer 2 (BN1+ReLU and BN-param derivation fused into GEMM2) ----
    k_gemm<1> <<<(N + 63) / 64, 256, 0, stream>>>(abuf, WT2, sums, g1, be1, dinv, hbuf, N, invn);
    k_gather  <<<(C0 + 3) / 4, 256, 0, stream>>>((const uint*)hbuf, offs, csr, dinv, b2, (uint*)abuf, 0,  C0);
    k_gather  <<<(C1 + 3) / 4, 256, 0, stream>>>((const uint*)hbuf, offs, csr, dinv, b2, (uint*)abuf, T1, C1);
    k_gather  <<<(C2 + 3) / 4, 256, 0, stream>>>((const uint*)hbuf, offs, csr, dinv, b2, (uint*)abuf, T2, C2);
    k_stats   <<<512, 256, 0, stream>>>((const uint*)abuf, N, sums + 256);

    // ---- head (BN2 derived in-block) ----
    k_final<<<(N + 15) / 16, 1024, 0, stream>>>((const uint*)abuf, sums + 256, g2, be2, Wl, bl, (float*)d_out, N, invn);
}

// Round 10
// 314.651 us; speedup vs baseline: 1.2556x; 1.2006x over previous
//
#include <hip/hip_runtime.h>
#include <cstdint>
#include <cstddef>

typedef unsigned int uint;
typedef unsigned short ushort;
typedef __attribute__((ext_vector_type(8))) short bf16x8;
typedef __attribute__((ext_vector_type(4))) float f32x4;

__device__ __forceinline__ ushort f2bf(float f) {          // RNE float->bf16
    uint b = __float_as_uint(f);
    return (ushort)((b + 0x7FFF + ((b >> 16) & 1)) >> 16);
}
__device__ __forceinline__ float bf_lo(uint u) { return __uint_as_float(u << 16); }
__device__ __forceinline__ float bf_hi(uint u) { return __uint_as_float(u & 0xFFFF0000u); }

// ============ CSR build via bucketed counting sort (no global atomics) ======
// bucket b = dst >> 8. NBKT <= 512, CHUNK <= 8192 assumed.

// P1: per-block coarse histogram -> cnt2d[b*256 + blk]; blocks >=256 do W-prep.
__global__ __launch_bounds__(256) void k_bcount(
        const int* __restrict__ dst, int E, int chunk,
        int* __restrict__ cnt2d, int nbkt,
        const float* __restrict__ W1, const float* __restrict__ W2,
        ushort* __restrict__ WT1, ushort* __restrict__ WT2,
        float* __restrict__ sums) {
    __shared__ int hist[512];
    if (blockIdx.x >= 256) {                    // fused weight prep + sums zero
        int idx = (blockIdx.x - 256) * 256 + threadIdx.x;   // 0..32767
        if (idx < 512) sums[idx] = 0.f;
        int nn = (idx >> 7) & 127, k = idx & 127;
        if (idx < 16384) WT1[idx] = f2bf(W1[k * 128 + nn]);
        else             WT2[idx - 16384] = f2bf(W2[k * 128 + nn]);
        return;
    }
    for (int b = threadIdx.x; b < nbkt; b += 256) hist[b] = 0;
    __syncthreads();
    const int beg = blockIdx.x * chunk;
    const int end = min(beg + chunk, E);
    for (int i = beg + threadIdx.x; i < end; i += 256)
        atomicAdd(&hist[dst[i] >> 8], 1);
    __syncthreads();
    for (int b = threadIdx.x; b < nbkt; b += 256)
        cnt2d[b * 256 + blockIdx.x] = hist[b];
}

// P2: LDS-staged scatter — locally bucket-sort the chunk, then write each
// (bucket,block) slice as a contiguous run.
__global__ __launch_bounds__(256) void k_bscatter(
        const int* __restrict__ src, const int* __restrict__ dst, int E, int chunk,
        const int* __restrict__ cnt2d, const int* __restrict__ cnt2dx,
        uint* __restrict__ ebuf, int nbkt) {
    __shared__ uint   ebuf_l[8192];
    __shared__ ushort bid_l[8192];
    __shared__ int    sh[256];
    __shared__ int    histx[512];
    __shared__ int    cur[512];
    __shared__ int    goff[512];
    const int t   = threadIdx.x;
    const int blk = blockIdx.x;

    const int b0 = 2 * t, b1 = 2 * t + 1;
    const int c0 = (b0 < nbkt) ? cnt2d[b0 * 256 + blk] : 0;
    const int c1 = (b1 < nbkt) ? cnt2d[b1 * 256 + blk] : 0;
    sh[t] = c0 + c1;
    __syncthreads();
    #pragma unroll
    for (int o = 1; o < 256; o <<= 1) {
        int x = (t >= o) ? sh[t - o] : 0;
        __syncthreads();
        sh[t] += x;
        __syncthreads();
    }
    const int ex = sh[t] - (c0 + c1);
    histx[b0] = ex;       histx[b1] = ex + c0;
    cur[b0]   = ex;       cur[b1]   = ex + c0;
    goff[b0] = ((b0 < nbkt) ? cnt2dx[b0 * 256 + blk] : 0) - histx[b0];
    goff[b1] = ((b1 < nbkt) ? cnt2dx[b1 * 256 + blk] : 0) - histx[b1];
    __syncthreads();

    const int beg = blk * chunk;
    const int end = min(beg + chunk, E);
    for (int i = beg + t; i < end; i += 256) {
        int d = dst[i];
        int s = src[i];
        int b = d >> 8;
        int p = atomicAdd(&cur[b], 1);            // LDS atomic
        ebuf_l[p] = ((uint)(d & 255) << 17) | (uint)s;
        bid_l[p]  = (ushort)b;
    }
    __syncthreads();

    const int cntE = end - beg;
    for (int i = t; i < cntE; i += 256)
        ebuf[goff[bid_l[i]] + i] = ebuf_l[i];
}

// P3: one block per bucket: fine counts -> dinv, offs, grouped csr
__global__ __launch_bounds__(256) void k_bcsr(
        const uint* __restrict__ ebuf, const int* __restrict__ cnt2dx,
        int E, int n, int nbkt,
        float* __restrict__ dinv, int* __restrict__ offs, int* __restrict__ csr) {
    __shared__ int fine[256], finex[256], fcur[256];
    const int b = blockIdx.x;
    const int t = threadIdx.x;
    const int ebeg = cnt2dx[b * 256];
    const int eend = (b + 1 < nbkt) ? cnt2dx[(b + 1) * 256] : E;
    fine[t] = 0;
    __syncthreads();
    for (int i = ebeg + t; i < eend; i += 256)
        atomicAdd(&fine[ebuf[i] >> 17], 1);
    __syncthreads();
    const int node = b * 256 + t;
    if (node < n) dinv[node] = rsqrtf((float)(fine[t] + 1));
    int v = fine[t];
    finex[t] = v;
    __syncthreads();
    #pragma unroll
    for (int o = 1; o < 256; o <<= 1) {
        int x = (t >= o) ? finex[t - o] : 0;
        __syncthreads();
        finex[t] += x;
        __syncthreads();
    }
    const int ex = finex[t] - v;
    fcur[t] = ex;
    if (node <= n) offs[node] = ebeg + ex;
    if (b == 0 && t == 0) offs[n] = E;
    __syncthreads();
    for (int i = ebeg + t; i < eend; i += 256) {
        uint e = ebuf[i];
        int f = (int)(e >> 17);
        int p = atomicAdd(&fcur[f], 1);             // LDS atomic
        csr[ebeg + p] = (int)(e & 0x1FFFF);
    }
}

// ---------------- hierarchical exclusive scan (used on cnt2d) --------------
__global__ __launch_bounds__(256) void k_scan_local(
        const int* __restrict__ cnt, int n,
        int* __restrict__ offs, int* __restrict__ bsum) {
    __shared__ int sh[256];
    const int base = blockIdx.x * 1024 + threadIdx.x * 4;
    int v[4];
    #pragma unroll
    for (int j = 0; j < 4; j++) { int g = base + j; v[j] = (g < n) ? cnt[g] : 0; }
    const int tsum = v[0] + v[1] + v[2] + v[3];
    sh[threadIdx.x] = tsum;
    __syncthreads();
    #pragma unroll
    for (int o = 1; o < 256; o <<= 1) {
        int t = (threadIdx.x >= (unsigned)o) ? sh[threadIdx.x - o] : 0;
        __syncthreads();
        sh[threadIdx.x] += t;
        __syncthreads();
    }
    int run = sh[threadIdx.x] - tsum;
    #pragma unroll
    for (int j = 0; j < 4; j++) {
        int g = base + j;
        if (g < n) offs[g] = run;
        run += v[j];
    }
    if (threadIdx.x == 255) bsum[blockIdx.x] = sh[255];
}

// add-back; each block derives its own prefix from bsum (nb <= 256)
__global__ __launch_bounds__(256) void k_scan_add(
        int* __restrict__ offs, int n, const int* __restrict__ bsum, int nb) {
    __shared__ int red[256];
    const int t = threadIdx.x;
    red[t] = (t < nb && t < (int)blockIdx.x) ? bsum[t] : 0;
    __syncthreads();
    #pragma unroll
    for (int o = 128; o; o >>= 1) {
        if (t < o) red[t] += red[t + o];
        __syncthreads();
    }
    const int add = red[0];
    const int base = blockIdx.x * 1024;
    #pragma unroll
    for (int j = 0; j < 4; j++) {
        int g = base + t + j * 256;
        if (g < n) offs[g] += add;
    }
}

// ---------------- MFMA GEMM, WT LDS-resident (XOR-swizzled) -----------------
// C[n,128](bf16) = dinv[r] * f(A) @ W.
// LAYER 0: A fp32, f=identity. LAYER 1: A bf16, f=relu(BN(a)), BN derived here.
template <int LAYER>
__global__ __launch_bounds__(256) void k_gemm(
        const void* __restrict__ Av, const ushort* __restrict__ WT,
        const float* __restrict__ sums, const float* __restrict__ g,
        const float* __restrict__ be, const float* __restrict__ dinv,
        ushort* __restrict__ C, int n, float invn) {
    __shared__ ushort sWT[128 * 128];   // 32 KB, rows XOR-swizzled by (row&7)<<4
    __shared__ float  ssl[256];
    const int tid  = threadIdx.x;
    const int lane = tid & 63;
    const int wid  = tid >> 6;
    const int m0   = blockIdx.x * 64 + wid * 16;
    const int lm   = lane & 15;
    const int lq   = lane >> 4;
    const int row  = m0 + lm;
    const bool rv  = row < n;

    // ---- issue A loads first (stay in flight across WT staging) ----
    float4 a0f[8];
    uint4  a1u[4];
    if (LAYER == 0) {
        const float* A = (const float*)Av;
        #pragma unroll
        for (int ks = 0; ks < 4; ks++) {
            const int kb = ks * 32 + lq * 8;
            if (rv) {
                a0f[2 * ks]     = *(const float4*)&A[(size_t)row * 128 + kb];
                a0f[2 * ks + 1] = *(const float4*)&A[(size_t)row * 128 + kb + 4];
            } else {
                a0f[2 * ks] = make_float4(0.f, 0.f, 0.f, 0.f);
                a0f[2 * ks + 1] = a0f[2 * ks];
            }
        }
    } else {
        const uint* A = (const uint*)Av;
        #pragma unroll
        for (int ks = 0; ks < 4; ks++) {
            const int kb = ks * 32 + lq * 8;
            a1u[ks] = rv ? *(const uint4*)&A[(size_t)row * 64 + kb / 2]
                         : make_uint4(0, 0, 0, 0);
        }
    }

    // ---- stage WT -> LDS with XOR swizzle (reg-staged, both sides swizzled) --
    {
        const uint4* WT4 = (const uint4*)WT;
        char* sB = (char*)sWT;
        #pragma unroll
        for (int i = 0; i < 8; i++) {
            int idx  = tid + i * 256;             // 0..2047 uint4
            uint4 v  = WT4[idx];
            int nrow = idx >> 4, j = idx & 15;
            int byte = (nrow * 256 + j * 16) ^ ((nrow & 7) << 4);
            *(uint4*)(sB + byte) = v;
        }
    }
    if (LAYER == 1 && tid < 128) {
        float mean = sums[tid] * invn;
        float var  = sums[128 + tid] * invn - mean * mean;
        float inv  = rsqrtf(var + 1e-5f);
        float sc   = g[tid] * inv;
        ssl[tid]       = sc;
        ssl[128 + tid] = be[tid] - mean * sc;
    }
    __syncthreads();

    f32x4 acc[8];
    #pragma unroll
    for (int i = 0; i < 8; i++) acc[i] = (f32x4){0.f, 0.f, 0.f, 0.f};

    const char* sB = (const char*)sWT;
    #pragma unroll
    for (int ks = 0; ks < 4; ks++) {
        const int kb = ks * 32 + lq * 8;
        bf16x8 af;
        if (LAYER == 0) {
            float4 v0 = a0f[2 * ks], v1 = a0f[2 * ks + 1];
            af[0] = (short)f2bf(v0.x); af[1] = (short)f2bf(v0.y);
            af[2] = (short)f2bf(v0.z); af[3] = (short)f2bf(v0.w);
            af[4] = (short)f2bf(v1.x); af[5] = (short)f2bf(v1.y);
            af[6] = (short)f2bf(v1.z); af[7] = (short)f2bf(v1.w);
        } else {
            uint4 u = a1u[ks];
            float4 sc0 = *(const float4*)&ssl[kb];
            float4 sc1 = *(const float4*)&ssl[kb + 4];
            float4 sh0 = *(const float4*)&ssl[128 + kb];
            float4 sh1 = *(const float4*)&ssl[128 + kb + 4];
            float f0 = fmaxf(fmaf(bf_lo(u.x), sc0.x, sh0.x), 0.f);
            float f1 = fmaxf(fmaf(bf_hi(u.x), sc0.y, sh0.y), 0.f);
            float f2 = fmaxf(fmaf(bf_lo(u.y), sc0.z, sh0.z), 0.f);
            float f3 = fmaxf(fmaf(bf_hi(u.y), sc0.w, sh0.w), 0.f);
            float f4 = fmaxf(fmaf(bf_lo(u.z), sc1.x, sh1.x), 0.f);
            float f5 = fmaxf(fmaf(bf_hi(u.z), sc1.y, sh1.y), 0.f);
            float f6 = fmaxf(fmaf(bf_lo(u.w), sc1.z, sh1.z), 0.f);
            float f7 = fmaxf(fmaf(bf_hi(u.w), sc1.w, sh1.w), 0.f);
            af[0] = (short)f2bf(f0); af[1] = (short)f2bf(f1);
            af[2] = (short)f2bf(f2); af[3] = (short)f2bf(f3);
            af[4] = (short)f2bf(f4); af[5] = (short)f2bf(f5);
            af[6] = (short)f2bf(f6); af[7] = (short)f2bf(f7);
        }
        #pragma unroll
        for (int nt = 0; nt < 8; nt++) {
            const int r    = nt * 16 + lm;
            const int byte = (r * 256 + ks * 64 + lq * 16) ^ ((r & 7) << 4);
            bf16x8 bfr = *(const bf16x8*)(sB + byte);
            acc[nt] = __builtin_amdgcn_mfma_f32_16x16x32_bf16(af, bfr, acc[nt], 0, 0, 0);
        }
    }

    const int orow0 = m0 + lq * 4;
    #pragma unroll
    for (int r = 0; r < 4; r++) {
        const int orow = orow0 + r;
        if (orow < n) {
            const float s = dinv[orow];
            #pragma unroll
            for (int nt = 0; nt < 8; nt++)
                C[(size_t)orow * 128 + nt * 16 + lm] = f2bf(acc[nt][r] * s);
        }
    }
}

// ---------------- gather-aggregate: wave per node, uint4 lanes --------------
__global__ __launch_bounds__(256) void k_gather(
        const uint* __restrict__ hs, const int* __restrict__ offs,
        const int* __restrict__ csr, const float* __restrict__ dinv,
        const float* __restrict__ bias, uint* __restrict__ out, int n) {
    const int node = (blockIdx.x * 256 + threadIdx.x) >> 6;
    if (node >= n) return;
    const int lane = threadIdx.x & 63;
    const int q  = lane & 15;
    const int eg = lane >> 4;
    const int beg = offs[node], end = offs[node + 1];
    const uint4* hs4 = (const uint4*)hs;

    float acc[8];
    if (eg == 0) {                               // self loop (prescaled rows)
        uint4 sv = hs4[(size_t)node * 16 + q];
        acc[0] = bf_lo(sv.x); acc[1] = bf_hi(sv.x);
        acc[2] = bf_lo(sv.y); acc[3] = bf_hi(sv.y);
        acc[4] = bf_lo(sv.z); acc[5] = bf_hi(sv.z);
        acc[6] = bf_lo(sv.w); acc[7] = bf_hi(sv.w);
    } else {
        #pragma unroll
        for (int j = 0; j < 8; j++) acc[j] = 0.f;
    }

    for (int e = beg + eg; e < end; e += 4) {
        const int s = csr[e];
        uint4 v = hs4[(size_t)s * 16 + q];
        acc[0] += bf_lo(v.x); acc[1] += bf_hi(v.x);
        acc[2] += bf_lo(v.y); acc[3] += bf_hi(v.y);
        acc[4] += bf_lo(v.z); acc[5] += bf_hi(v.z);
        acc[6] += bf_lo(v.w); acc[7] += bf_hi(v.w);
    }

    #pragma unroll
    for (int j = 0; j < 8; j++) {
        acc[j] += __shfl_xor(acc[j], 16);
        acc[j] += __shfl_xor(acc[j], 32);
    }

    if (eg == 0) {
        const float di = dinv[node];
        const float4 b0 = *(const float4*)&bias[q * 8];
        const float4 b1 = *(const float4*)&bias[q * 8 + 4];
        uint4 o;
        o.x = (uint)f2bf(fmaf(di, acc[0], b0.x)) | ((uint)f2bf(fmaf(di, acc[1], b0.y)) << 16);
        o.y = (uint)f2bf(fmaf(di, acc[2], b0.z)) | ((uint)f2bf(fmaf(di, acc[3], b0.w)) << 16);
        o.z = (uint)f2bf(fmaf(di, acc[4], b1.x)) | ((uint)f2bf(fmaf(di, acc[5], b1.y)) << 16);
        o.w = (uint)f2bf(fmaf(di, acc[6], b1.z)) | ((uint)f2bf(fmaf(di, acc[7], b1.w)) << 16);
        ((uint4*)out)[(size_t)node * 16 + q] = o;
    }
}

// ---------------- BN stats (packed uint loads) ----------------
__global__ __launch_bounds__(256) void k_stats(
        const uint* __restrict__ h, int n, float* __restrict__ sums) {
    const int j   = threadIdx.x & 63;
    const int sub = threadIdx.x >> 6;
    float slo = 0.f, s2lo = 0.f, shi = 0.f, s2hi = 0.f;
    for (int r = blockIdx.x * 4 + sub; r < n; r += gridDim.x * 4) {
        uint u = h[(size_t)r * 64 + j];
        float a = bf_lo(u), b = bf_hi(u);
        slo += a; s2lo = fmaf(a, a, s2lo);
        shi += b; s2hi = fmaf(b, b, s2hi);
    }
    __shared__ float sh[4][256];
    sh[0][threadIdx.x] = slo; sh[1][threadIdx.x] = s2lo;
    sh[2][threadIdx.x] = shi; sh[3][threadIdx.x] = s2hi;
    __syncthreads();
    if (sub == 0) {
        float a0 = 0.f, a1 = 0.f, a2 = 0.f, a3 = 0.f;
        #pragma unroll
        for (int t = 0; t < 4; t++) {
            a0 += sh[0][t * 64 + j]; a1 += sh[1][t * 64 + j];
            a2 += sh[2][t * 64 + j]; a3 += sh[3][t * 64 + j];
        }
        atomicAdd(&sums[2 * j],           a0);
        atomicAdd(&sums[128 + 2 * j],     a1);
        atomicAdd(&sums[2 * j + 1],       a2);
        atomicAdd(&sums[128 + 2 * j + 1], a3);
    }
}

// ---------------- head (BN2 derived in-block) --------------
__global__ __launch_bounds__(1024) void k_final(
        const uint* __restrict__ h, const float* __restrict__ sums,
        const float* __restrict__ g, const float* __restrict__ be,
        const float* __restrict__ Wl, const float* __restrict__ bl,
        float* __restrict__ out, int n, float invn) {
    __shared__ float ssl[256];
    const int t = threadIdx.x;
    if (t < 128) {
        float mean = sums[t] * invn;
        float var  = sums[128 + t] * invn - mean * mean;
        float inv  = rsqrtf(var + 1e-5f);
        float sc   = g[t] * inv;
        ssl[t]       = sc;
        ssl[128 + t] = be[t] - mean * sc;
    }
    __syncthreads();
    int node = (blockIdx.x * 1024 + t) >> 6;
    int lane = t & 63;
    if (node >= n) return;
    int c = lane * 2;
    uint v = h[(size_t)node * 64 + lane];
    float a0 = fmaxf(fmaf(bf_lo(v), ssl[c],     ssl[128 + c]),     0.f);
    float a1 = fmaxf(fmaf(bf_hi(v), ssl[c + 1], ssl[128 + c + 1]), 0.f);
    float p = a0 * Wl[c] + a1 * Wl[c + 1];
    #pragma unroll
    for (int o = 32; o; o >>= 1) p += __shfl_xor(p, o);
    if (lane == 0) {
        float z = fmaxf(p + bl[0], 0.f);
        out[node] = 1.f / (1.f + expf(-z));
    }
}

extern "C" void kernel_launch(void* const* d_in, const int* in_sizes, int n_in,
                              void* d_out, int out_size, void* d_ws, size_t ws_size,
                              hipStream_t stream) {
    const float* x   = (const float*)d_in[0];
    const int*   ei  = (const int*)d_in[1];
    const float* W1  = (const float*)d_in[2];
    const float* b1  = (const float*)d_in[3];
    const float* g1  = (const float*)d_in[4];
    const float* be1 = (const float*)d_in[5];
    const float* W2  = (const float*)d_in[6];
    const float* b2  = (const float*)d_in[7];
    const float* g2  = (const float*)d_in[8];
    const float* be2 = (const float*)d_in[9];
    const float* Wl  = (const float*)d_in[10];
    const float* bl  = (const float*)d_in[11];

    const int N = in_sizes[0] / 128;
    const int E = in_sizes[1] / 2;
    const int* src  = ei;
    const int* dstp = ei + E;

    const int NBKT  = (N + 255) >> 8;
    const int n2    = NBKT * 256;
    const int NB2   = (n2 + 1023) / 1024;
    const int CHUNK = (E + 255) / 256;

    char* ws = (char*)d_ws;
    size_t off = 0;
    auto alloc = [&](size_t bytes) {
        void* p = ws + off;
        off += (bytes + 255) & ~(size_t)255;
        return p;
    };
    float*  dinv   = (float*) alloc((size_t)N * 4);
    int*    offs   = (int*)   alloc((size_t)(N + 1) * 4);
    int*    cnt2d  = (int*)   alloc((size_t)n2 * 4);
    int*    cnt2dx = (int*)   alloc((size_t)n2 * 4);
    int*    bsum   = (int*)   alloc(1024 * 4);
    uint*   ebuf   = (uint*)  alloc((size_t)E * 4);
    int*    csr    = (int*)   alloc((size_t)E * 4);
    float*  sums   = (float*) alloc(512 * 4);
    ushort* WT1    = (ushort*)alloc(128 * 128 * 2);
    ushort* WT2    = (ushort*)alloc(128 * 128 * 2);
    ushort* hbuf   = (ushort*)alloc((size_t)N * 128 * 2);
    ushort* abuf   = (ushort*)alloc((size_t)N * 128 * 2);

    const float invn = 1.f / (float)N;

    // ---- CSR build (bucketed counting sort) + fused weight prep ----
    k_bcount    <<<384, 256, 0, stream>>>(dstp, E, CHUNK, cnt2d, NBKT,
                                          W1, W2, WT1, WT2, sums);
    k_scan_local<<<NB2, 256, 0, stream>>>(cnt2d, n2, cnt2dx, bsum);
    k_scan_add  <<<NB2, 256, 0, stream>>>(cnt2dx, n2, bsum, NB2);
    k_bscatter  <<<256, 256, 0, stream>>>(src, dstp, E, CHUNK, cnt2d, cnt2dx, ebuf, NBKT);
    k_bcsr      <<<NBKT, 256, 0, stream>>>(ebuf, cnt2dx, E, N, NBKT, dinv, offs, csr);

    // ---- layer 1 ----
    k_gemm<0> <<<(N + 63) / 64, 256, 0, stream>>>(x, WT1, nullptr, nullptr, nullptr, dinv, hbuf, N, invn);
    k_gather  <<<(N + 3) / 4, 256, 0, stream>>>((const uint*)hbuf, offs, csr, dinv, b1, (uint*)abuf, N);
    k_stats   <<<512, 256, 0, stream>>>((const uint*)abuf, N, sums);

    // ---- layer 2 (BN1+ReLU and BN-param derivation fused into GEMM2) ----
    k_gemm<1> <<<(N + 63) / 64, 256, 0, stream>>>(abuf, WT2, sums, g1, be1, dinv, hbuf, N, invn);
    k_gather  <<<(N + 3) / 4, 256, 0, stream>>>((const uint*)hbuf, offs, csr, dinv, b2, (uint*)abuf, N);
    k_stats   <<<512, 256, 0, stream>>>((const uint*)abuf, N, sums + 256);

    // ---- head (BN2 derived in-block) ----
    k_final<<<(N + 15) / 16, 1024, 0, stream>>>((const uint*)abuf, sums + 256, g2, be2, Wl, bl, (float*)d_out, N, invn);
}